// Round 4
// baseline (347.164 us; speedup 1.0000x reference)
//
#include <hip/hip_runtime.h>
#include <stdint.h>

#define BDIM 64
#define SDIM 1024
#define EDIM 512
#define ADIM 128
#define KDIM 1024                // 2E
#define NDIM 1024                // 2E

typedef unsigned short u16;
typedef __attribute__((ext_vector_type(8))) short short8;
typedef __attribute__((ext_vector_type(4))) float floatx4;
typedef const __attribute__((address_space(1))) void as1_void;
typedef __attribute__((address_space(3))) void as3_void;

__device__ inline u16 f2bf(float f){
  unsigned int u = __float_as_uint(f);
  u += 0x7fffu + ((u >> 16) & 1u);
  return (u16)(u >> 16);
}

// ================= prep kernel: role-split by blockIdx =================
// [0,1024): cast states->bf16 (live rows)   [1024,1280): W1p transpose + zero scores
// 1280: row compaction (cum + rows map)     [1281,1537): sym stage1
// [1537,1601): value head
__global__ __launch_bounds__(1024) void k_prep(
    const float* __restrict__ states, const float* __restrict__ cls,
    const float* __restrict__ W1p, const float* __restrict__ W1s,
    const float* __restrict__ b1s, const float* __restrict__ Wc1,
    const float* __restrict__ bc1, const float* __restrict__ wc2,
    const float* __restrict__ bc2, const int* __restrict__ lengths,
    const int* __restrict__ pos_action,
    u16* __restrict__ sbf, u16* __restrict__ wt,
    float* __restrict__ sh, int* __restrict__ rows, int* __restrict__ aux,
    float* __restrict__ scores, float* __restrict__ out)
{
  __shared__ float smem[64*65];
  const int blk = blockIdx.x, tid = threadIdx.x;

  if (blk < 1024){
    int i = blk*1024 + tid;
#pragma unroll
    for (int it = 0; it < 4; ++it, i += 1048576){
      int row = i >> 6;
      int s = row & 1023, b = row >> 10;
      if (s < lengths[b]){
        const float4* sp = (const float4*)states + (size_t)i*2;
        float4 a = sp[0], c = sp[1];
        short8 v;
        v[0]=(short)f2bf(a.x); v[1]=(short)f2bf(a.y); v[2]=(short)f2bf(a.z); v[3]=(short)f2bf(a.w);
        v[4]=(short)f2bf(c.x); v[5]=(short)f2bf(c.y); v[6]=(short)f2bf(c.z); v[7]=(short)f2bf(c.w);
        ((short8*)sbf)[i] = v;
      }
    }
    return;
  }
  if (blk < 1280){
    float (*tile)[65] = (float(*)[65])smem;
    int tb = blk - 1024;
    // fused: zero compact scores (65536 floats; only tb<64 blocks write)
    int zi = tb*1024 + tid;
    if (zi < 65536) scores[zi] = 0.f;
    int k0 = (tb & 15)*64, n0 = (tb >> 4)*64;
    int tx = tid & 63, ty = tid >> 6;
    for (int j = ty; j < 64; j += 16) tile[j][tx] = W1p[(size_t)(k0+j)*NDIM + n0 + tx];
    __syncthreads();
    for (int j = ty; j < 64; j += 16) wt[(size_t)(n0+j)*KDIM + k0 + tx] = f2bf(tile[tx][j]);
    return;
  }
  if (blk == 1280){
    // ---- row compaction: cum[b] = sum_{b'<b}(len-1); rows[cum[b]+s] = b*1024+s ----
    __shared__ int scum[65];
    if (tid == 0){
      int c = 0;
      for (int b = 0; b < 64; ++b){ scum[b] = c; c += lengths[b] - 1; }
      scum[64] = c;
    }
    __syncthreads();
    if (tid < 65) aux[tid] = scum[tid];
    if (tid == 0){
      aux[70] = scum[64];                 // total live rows
      aux[71] = (scum[64] + 127) >> 7;    // ntiles (128)
      aux[72] = (scum[64] + 255) >> 8;    // ntiles (256) for the 8-phase gemm
    }
    for (int b = 0; b < 64; ++b){
      int base = scum[b], L = scum[b+1] - scum[b];
      for (int i2 = tid; i2 < L; i2 += 1024) rows[base + i2] = (b << 10) + i2;
    }
    return;
  }
  if (blk < 1537){
    float* xs  = smem;
    float* red = smem + 1024;
    int rb = blk - 1281;
    int b = rb >> 2, n0 = (rb & 3)*256;
    int pa = pos_action[b];
    const float* src = states + (size_t)(b*SDIM + pa) * EDIM;
    xs[tid] = src[tid];
    __syncthreads();
    int n = n0 + (tid & 255);
    int k0 = (tid >> 8) * 256;
    float acc = 0.f;
#pragma unroll 8
    for (int jj = 0; jj < 256; ++jj){
      int k = k0 + jj;
      acc = fmaf(xs[k], W1s[(size_t)k*1024 + n], acc);
    }
    red[tid] = acc;
    __syncthreads();
    if (tid < 256){
      float s = red[tid] + red[tid+256] + red[tid+512] + red[tid+768];
      sh[b*1024 + n0 + tid] = fmaxf(s + b1s[n0 + tid], 0.f);
    }
    return;
  }
  {
    float* xs  = smem;
    float* red = smem + 512;
    float* r2  = smem + 1536;
    int b = blk - 1537;
    if (tid < 512) xs[tid] = cls[b*EDIM + tid];
    __syncthreads();
    int n = tid & 511;
    int k0 = (tid >> 9) * 256;
    float acc = 0.f;
#pragma unroll 8
    for (int jj = 0; jj < 256; ++jj){
      int k = k0 + jj;
      acc = fmaf(xs[k], Wc1[(size_t)k*EDIM + n], acc);
    }
    red[tid] = acc;
    __syncthreads();
    float p = 0.f;
    if (tid < 512){
      float h = red[tid] + red[tid + 512];
      p = fmaxf(h + bc1[tid], 0.f) * wc2[tid];
    }
    for (int off = 32; off; off >>= 1) p += __shfl_xor(p, off);
    if ((tid & 63) == 0) r2[tid >> 6] = p;
    __syncthreads();
    if (tid == 0){
      float s = bc2[0];
#pragma unroll
      for (int jj = 0; jj < 16; ++jj) s += r2[jj];
      out[128 + b] = s;
    }
  }
}

// ================= main GEMM: 256x256 tile, 8 waves, 4-phase/K-tile counted-vmcnt =================
// BM=BN=256, BK=64, K=1024 -> 16 K-tiles. LDS 128 KiB = 2 slots x (A 32K | B 32K),
// each matrix split in kh halves (32 K-elems = 16 KiB, contiguous for global_load_lds).
// Stage schedule per K-tile t: p0:Akh1(t+1) p1:Bkh1(t+1) p2:Akh0(t+2) p3:Bkh0(t+2);
// counted waits vmcnt(4) at end of p1 and p3 (FIFO ledger: guarantees each half
// resident >=1 phase before first ds_read; >=4 loads always in flight; never vmcnt(0)).
// LDS chunk swizzle q^((r>>2)&3) (2 lanes/bank-slot per quarter-wave = free) with the
// inverse swizzle applied on the global source addresses (both-sides rule).
__global__ __launch_bounds__(512, 2) void k_gemm_scores(
    const u16* __restrict__ sbf, const u16* __restrict__ wt,
    const float* __restrict__ b1p, const float* __restrict__ w2p,
    const int* __restrict__ rows, const int* __restrict__ aux,
    float* __restrict__ scores)
{
  __shared__ short8 L[8192];   // 128 KiB
  const int tid = threadIdx.x;
  const int w = tid >> 6, l = tid & 63;
  const int j = blockIdx.x;
  const int tl = ((j >> 5) << 3) | (j & 7);   // XCD phase = j&7; 4 nt-variants share XCD
  const int nt = (j >> 3) & 3;
  const int total = aux[70];
  if (tl >= aux[72]) return;

  // ---- stage source offsets (per thread, two 16B instructions per half-stage) ----
  const int swzc = ((tid & 3) ^ ((tid >> 4) & 3)) * 16;
  unsigned int srcA0, srcA1, srcB0, srcB1;
  {
    int rl0 = (tid >> 2), rl1 = 128 + (tid >> 2);
    int mg0 = tl*256 + rl0; if (mg0 >= total) mg0 = 0;
    int mg1 = tl*256 + rl1; if (mg1 >= total) mg1 = 0;
    srcA0 = (unsigned)rows[mg0]*1024u + (unsigned)swzc;   // A row stride 1024 B
    srcA1 = (unsigned)rows[mg1]*1024u + (unsigned)swzc;
    srcB0 = (unsigned)(nt*256 + rl0)*2048u + (unsigned)swzc; // Wt row stride 2048 B
    srcB1 = (unsigned)(nt*256 + rl1)*2048u + (unsigned)swzc;
  }
  const char* sb = (const char*)sbf;
  const char* wb = (const char*)wt;
  char* Lb = (char*)L;
  const int ldsw = w*1024;   // wave's 1 KiB chunk within an 8 KiB u-half

#define STG(ga, lo) __builtin_amdgcn_global_load_lds((as1_void*)(ga), (as3_void*)(Lb + (lo)), 16, 0, 0)
#define STAGE_A(kt, kh, slot) do{ unsigned go = (unsigned)(kt)*128u + (unsigned)(kh)*64u; \
    STG(sb + srcA0 + go, (slot)*65536 + (kh)*16384 +        ldsw); \
    STG(sb + srcA1 + go, (slot)*65536 + (kh)*16384 + 8192 + ldsw); }while(0)
#define STAGE_B(kt, kh, slot) do{ unsigned go = (unsigned)(kt)*128u + (unsigned)(kh)*64u; \
    STG(wb + srcB0 + go, (slot)*65536 + 32768 + (kh)*16384 +        ldsw); \
    STG(wb + srcB1 + go, (slot)*65536 + 32768 + (kh)*16384 + 8192 + ldsw); }while(0)
#define BARRIER __builtin_amdgcn_s_barrier()
#define LGKM0 do{ asm volatile("s_waitcnt lgkmcnt(0)" ::: "memory"); __builtin_amdgcn_sched_barrier(0); }while(0)
#define VM4 do{ __builtin_amdgcn_sched_barrier(0); asm volatile("s_waitcnt vmcnt(4)" ::: "memory"); }while(0)

  // ---- fragment read offsets (short8 units; row = 4 short8 = 64 B) ----
  const int r = l & 15, q = l >> 4;
  const int wm = w & 1, wn = w >> 1;
  const int fsw = q ^ ((r >> 2) & 3);
  const int aB = (wm*128 + r)*4 + fsw;           // + mi*64 + kh*1024 + slot*4096
  const int bB = 2048 + (wn*64 + r)*4 + fsw;     // + ni*64 + kh*1024 + slot*4096

  floatx4 acc[8][4];
#pragma unroll
  for (int a = 0; a < 8; ++a)
#pragma unroll
    for (int b = 0; b < 4; ++b) acc[a][b] = (floatx4)(0.0f);

  // ---- prologue: tile0 (kh0+kh1) + tile1 kh0 = 12 loads; drain tile0, keep 4 in flight ----
  STAGE_A(0,0,0); STAGE_B(0,0,0);
  STAGE_A(0,1,0); STAGE_B(0,1,0);
  STAGE_A(1,0,1); STAGE_B(1,0,1);
  __builtin_amdgcn_sched_barrier(0);
  asm volatile("s_waitcnt vmcnt(4)" ::: "memory");
  BARRIER;

  short8 af[4], bf[4];
#pragma unroll 2
  for (int t = 0; t < 16; ++t){
    const int s  = t & 1;
    const int so = s ^ 1;
    const int sb16 = s*4096;
    const int kt1 = (t+1) & 15, kt2 = (t+2) & 15;  // tail stages wrap (garbage, never read)

    // -------- phase 0: kh0, mi 0-3 (reads B kh0) --------
#pragma unroll
    for (int i = 0; i < 4; ++i) af[i] = L[sb16 + aB + i*64];
#pragma unroll
    for (int i = 0; i < 4; ++i) bf[i] = L[sb16 + bB + i*64];
    STAGE_A(kt1, 1, so);
    BARRIER; LGKM0;
    __builtin_amdgcn_s_setprio(1);
#pragma unroll
    for (int mi = 0; mi < 4; ++mi)
#pragma unroll
      for (int ni = 0; ni < 4; ++ni)
        acc[mi][ni] = __builtin_amdgcn_mfma_f32_16x16x32_bf16(af[mi], bf[ni], acc[mi][ni], 0, 0, 0);
    __builtin_amdgcn_s_setprio(0);
    BARRIER;

    // -------- phase 1: kh0, mi 4-7 (keeps B) --------
#pragma unroll
    for (int i = 0; i < 4; ++i) af[i] = L[sb16 + aB + (4+i)*64];
    STAGE_B(kt1, 1, so);
    BARRIER; LGKM0;
    __builtin_amdgcn_s_setprio(1);
#pragma unroll
    for (int mi = 0; mi < 4; ++mi)
#pragma unroll
      for (int ni = 0; ni < 4; ++ni)
        acc[4+mi][ni] = __builtin_amdgcn_mfma_f32_16x16x32_bf16(af[mi], bf[ni], acc[4+mi][ni], 0, 0, 0);
    __builtin_amdgcn_s_setprio(0);
    VM4;        // drains kh0(t+1) -> resident for next tile's p0
    BARRIER;

    // -------- phase 2: kh1, mi 0-3 (reads B kh1) --------
#pragma unroll
    for (int i = 0; i < 4; ++i) af[i] = L[sb16 + 1024 + aB + i*64];
#pragma unroll
    for (int i = 0; i < 4; ++i) bf[i] = L[sb16 + 1024 + bB + i*64];
    STAGE_A(kt2, 0, s);
    BARRIER; LGKM0;
    __builtin_amdgcn_s_setprio(1);
#pragma unroll
    for (int mi = 0; mi < 4; ++mi)
#pragma unroll
      for (int ni = 0; ni < 4; ++ni)
        acc[mi][ni] = __builtin_amdgcn_mfma_f32_16x16x32_bf16(af[mi], bf[ni], acc[mi][ni], 0, 0, 0);
    __builtin_amdgcn_s_setprio(0);
    BARRIER;

    // -------- phase 3: kh1, mi 4-7 --------
#pragma unroll
    for (int i = 0; i < 4; ++i) af[i] = L[sb16 + 1024 + aB + (4+i)*64];
    STAGE_B(kt2, 0, s);
    BARRIER; LGKM0;
    __builtin_amdgcn_s_setprio(1);
#pragma unroll
    for (int mi = 0; mi < 4; ++mi)
#pragma unroll
      for (int ni = 0; ni < 4; ++ni)
        acc[4+mi][ni] = __builtin_amdgcn_mfma_f32_16x16x32_bf16(af[mi], bf[ni], acc[4+mi][ni], 0, 0, 0);
    __builtin_amdgcn_s_setprio(0);
    VM4;        // drains kh1(t+1) -> whole next tile resident at entry
    BARRIER;
  }
  __builtin_amdgcn_sched_barrier(0);
  asm volatile("s_waitcnt vmcnt(0)" ::: "memory");   // drain tail garbage stages before exit

#undef STG
#undef STAGE_A
#undef STAGE_B
#undef BARRIER
#undef LGKM0
#undef VM4

  // -------- epilogue: relu(h+b1p)*w2p, quad-reduce over n, atomicAdd compact scores --------
  const int mrow0 = tl*256 + wm*128;
  const int ncol0 = nt*256 + wn*64;
#pragma unroll
  for (int mi = 0; mi < 8; ++mi){
    float t0 = 0.f, t1 = 0.f, t2 = 0.f, t3 = 0.f;
#pragma unroll
    for (int ni = 0; ni < 4; ++ni){
      int n = ncol0 + ni*16 + r;
      float bb = b1p[n], ww = w2p[n];
      floatx4 a = acc[mi][ni];
      t0 += fmaxf(a[0] + bb, 0.f) * ww;
      t1 += fmaxf(a[1] + bb, 0.f) * ww;
      t2 += fmaxf(a[2] + bb, 0.f) * ww;
      t3 += fmaxf(a[3] + bb, 0.f) * ww;
    }
#pragma unroll
    for (int off = 1; off < 16; off <<= 1){
      t0 += __shfl_xor(t0, off);
      t1 += __shfl_xor(t1, off);
      t2 += __shfl_xor(t2, off);
      t3 += __shfl_xor(t3, off);
    }
    if (r == 0){
      int row = mrow0 + mi*16 + q*4;
      if (row + 0 < total) atomicAdd(&scores[row + 0], t0);
      if (row + 1 < total) atomicAdd(&scores[row + 1], t1);
      if (row + 2 < total) atomicAdd(&scores[row + 2], t2);
      if (row + 3 < total) atomicAdd(&scores[row + 3], t3);
    }
  }
}

// ================= post: pos softmax (blocks 0-63) + sym_out (64-127) =================
__global__ __launch_bounds__(1024) void k_post(
    const float* __restrict__ scores, const float* __restrict__ sh,
    const float* __restrict__ W2s, const float* __restrict__ b2s,
    const int* __restrict__ aux, const int* __restrict__ lengths,
    const int* __restrict__ pos_action, const int* __restrict__ sym_action,
    float* __restrict__ out)
{
  __shared__ float smem[2208];
  const int blk = blockIdx.x, tid = threadIdx.x;
  if (blk < 64){
    float* sc   = smem;
    float* red  = smem + 1024;
    float* red2 = smem + 1040;
    int b = blk;
    int L = lengths[b] - 1;
    const float* sp = scores + aux[b];   // compact base for batch b
    float mx = -1e30f;
    for (int s = tid; s < L; s += 1024){
      float v = sp[s];
      sc[s] = v;
      mx = fmaxf(mx, v);
    }
    for (int off = 32; off; off >>= 1) mx = fmaxf(mx, __shfl_xor(mx, off));
    if ((tid & 63) == 0) red[tid >> 6] = mx;
    __syncthreads();
    mx = -1e30f;
#pragma unroll
    for (int jj = 0; jj < 16; ++jj) mx = fmaxf(mx, red[jj]);
    float se = 0.f, ses = 0.f;
    for (int s = tid; s < L; s += 1024){
      float v = sc[s];
      float e = expf(v - mx);
      se += e; ses += e * v;
    }
    for (int off = 32; off; off >>= 1){ se += __shfl_xor(se, off); ses += __shfl_xor(ses, off); }
    __syncthreads();
    if ((tid & 63) == 0){ red[tid >> 6] = se; red2[tid >> 6] = ses; }
    __syncthreads();
    if (tid == 0){
      float S = 0.f, SS = 0.f;
#pragma unroll
      for (int jj = 0; jj < 16; ++jj){ S += red[jj]; SS += red2[jj]; }
      float logZ = logf(S);
      int pa = pos_action[b];
      out[b]       = sc[pa] - mx - logZ;
      out[192 + b] = mx + logZ - SS / S;
    }
    return;
  }
  {
    float* xs  = smem;
    float* red = smem + 1024;
    float* lg  = smem + 2048;
    float* r2  = smem + 2176;
    float* r3  = smem + 2192;
    int b = blk - 64;
    xs[tid] = sh[b*1024 + tid];
    __syncthreads();
    int n = tid & 127;
    int f0 = (tid >> 7) * 128;
    float acc = 0.f;
#pragma unroll 8
    for (int jj = 0; jj < 128; ++jj){
      int f = f0 + jj;
      acc = fmaf(xs[f], W2s[(size_t)f*ADIM + n], acc);
    }
    red[tid] = acc;
    __syncthreads();
    if (tid < 128){
      float s = b2s[tid];
#pragma unroll
      for (int jj = 0; jj < 8; ++jj) s += red[tid + jj*128];
      lg[tid] = s;
    }
    __syncthreads();
    float v = (tid < 128) ? lg[tid] : -1e30f;
    float mx = v;
    for (int off = 32; off; off >>= 1) mx = fmaxf(mx, __shfl_xor(mx, off));
    if ((tid & 63) == 0) r2[tid >> 6] = mx;
    __syncthreads();
    mx = -1e30f;
#pragma unroll
    for (int jj = 0; jj < 16; ++jj) mx = fmaxf(mx, r2[jj]);
    float e = (tid < 128) ? expf(v - mx) : 0.f;
    float se = e, ses = (tid < 128) ? e * v : 0.f;
    for (int off = 32; off; off >>= 1){ se += __shfl_xor(se, off); ses += __shfl_xor(ses, off); }
    __syncthreads();
    if ((tid & 63) == 0){ r2[tid >> 6] = se; r3[tid >> 6] = ses; }
    __syncthreads();
    if (tid == 0){
      float S = 0.f, SS = 0.f;
#pragma unroll
      for (int jj = 0; jj < 16; ++jj){ S += r2[jj]; SS += r3[jj]; }
      float logZ = logf(S);
      out[64 + b]  = lg[sym_action[b]] - mx - logZ;
      out[256 + b] = mx + logZ - SS / S;
    }
  }
}

extern "C" void kernel_launch(void* const* d_in, const int* in_sizes, int n_in,
                              void* d_out, int out_size, void* d_ws, size_t ws_size,
                              hipStream_t stream){
  const float* states = (const float*)d_in[0];
  const float* cls    = (const float*)d_in[1];
  const float* W1p    = (const float*)d_in[2];
  const float* b1p    = (const float*)d_in[3];
  const float* w2p    = (const float*)d_in[4];
  const float* W1s    = (const float*)d_in[6];
  const float* b1s    = (const float*)d_in[7];
  const float* W2s    = (const float*)d_in[8];
  const float* b2s    = (const float*)d_in[9];
  const float* Wc1    = (const float*)d_in[10];
  const float* bc1    = (const float*)d_in[11];
  const float* wc2    = (const float*)d_in[12];
  const float* bc2    = (const float*)d_in[13];
  const int* lengths  = (const int*)d_in[14];
  const int* pos_a    = (const int*)d_in[15];
  const int* sym_a    = (const int*)d_in[16];
  float* out = (float*)d_out;

  char* ws = (char*)d_ws;
  u16* sbf      = (u16*)ws;                      // 67108864 B (states bf16)
  u16* wt       = (u16*)(ws + 67108864);         //  2097152 B (W1p^T bf16)
  float* scores = (float*)(ws + 69206016);       //   262144 B (compact scores)
  float* sh     = (float*)(ws + 69468160);       //   262144 B (sym hidden)
  int* rows     = (int*)(ws + 69730304);         //   262144 B (compact row -> b*1024+s)
  int* aux      = (int*)(ws + 69992448);         //      320 B (cum[65], [70]=total, [71]/[72]=ntiles)

  k_prep<<<1601, 1024, 0, stream>>>(states, cls, W1p, W1s, b1s, Wc1, bc1, wc2, bc2,
                                    lengths, pos_a, sbf, wt, sh, rows, aux, scores, out);
  k_gemm_scores<<<1024, 512, 0, stream>>>(sbf, wt, b1p, w2p, rows, aux, scores);
  k_post<<<128, 1024, 0, stream>>>(scores, sh, W2s, b2s, aux, lengths, pos_a, sym_a, out);
}